// Round 3
// baseline (238.828 us; speedup 1.0000x reference)
//
#include <hip/hip_runtime.h>
#include <math.h>

// Problem constants
#define NQ     65536
#define DIM    256
#define NBATCH 512
#define KNN    200
#define NCLS   1000
#define TSELF  0.155f    // bf16-filter threshold (top-200 boundary ~0.171)
#define TSELH  0.150f    // histogram base for exact recomputed values
// bf16 dot err bound: |err| <= 2*2^-9*||a||*||b|| ~= 3.9e-3 (unit norms).
// Guard: selected boundary bin must have lower edge >= TSELF + 4.1e-3, i.e.
// bstar >= ceil((TSELF+0.0041-TSELH)/binw) = 22, else exact fallback.
#define BGUARD 22

#define GM  128
#define GK  32
#define NTN (NQ / GM)    // 512 bn tiles
#define KSTEPS (DIM / GK)

typedef unsigned short u16;
typedef unsigned long long u64;
typedef __attribute__((ext_vector_type(8))) short short8;
typedef __attribute__((ext_vector_type(4))) float f32x4;

// out layout: [0] accuracy | [1..1+NQ*DIM) features | [..+NQ) labels | [last] ptr

__device__ __forceinline__ u16 f2bf(float x) {
  unsigned u = __float_as_uint(x);
  return (u16)((u + 0x7FFFu + ((u >> 16) & 1u)) >> 16);
}
__device__ __forceinline__ void load_lds16(const void* g, void* l) {
  __builtin_amdgcn_global_load_lds(
      (const __attribute__((address_space(1))) unsigned int*)g,
      (__attribute__((address_space(3))) unsigned int*)l, 16, 0, 0);
}
// out+1 is 4B-aligned, ≡4 (mod 16): dword, dwordx2 (8-aligned), dword
__device__ __forceinline__ void store_f4u(float* p, float4 v) {
  p[0] = v.x;
  *(float2*)(p + 1) = make_float2(v.y, v.z);
  p[3] = v.w;
}

// ---------------------------------------------------------------------------
// 0. fused prep + queue-update copy. Reads qf ONCE; writes out features
//    (with the 512 replaced rows), out labels, ptr, bf16 B (queue) and
//    bf16 A (batch), zeroes flag[] and accuracy.
// ---------------------------------------------------------------------------
__global__ __launch_bounds__(256) void prep_copy_kernel(
    const float* __restrict__ feat, const int* __restrict__ labels,
    const float* __restrict__ qf, const int* __restrict__ ql,
    const int* __restrict__ qptr,
    u16* __restrict__ Bb, u16* __restrict__ Ab,
    int* __restrict__ flag, float* __restrict__ out)
{
  const int idx = blockIdx.x * 256 + threadIdx.x;   // float4 index, < NQ*DIM/4
  const int ptr = qptr[0];
  const long long NFEAT = (long long)NQ * DIM;

  // --- queue features: out = old queue except rows (ptr..ptr+511)%NQ ---
  {
    float4 qv = ((const float4*)qf)[idx];
    int row = idx >> 6;                 // / (DIM/4)
    int c4  = idx & 63;
    int d = (row - ptr) & (NQ - 1);
    float4 ov = qv;
    if (d < NBATCH) ov = ((const float4*)feat)[d * 64 + c4];
    store_f4u(out + 1 + 4 * (long long)idx, ov);

    // --- B bf16 (ALWAYS old queue values) ---
    ushort4 h;
    h.x = f2bf(qv.x); h.y = f2bf(qv.y); h.z = f2bf(qv.z); h.w = f2bf(qv.w);
    ((ushort4*)Bb)[idx] = h;
  }

  // --- A bf16 (batch features) ---
  if (idx < NBATCH * DIM / 4) {
    float4 v = ((const float4*)feat)[idx];
    ushort4 h;
    h.x = f2bf(v.x); h.y = f2bf(v.y); h.z = f2bf(v.z); h.w = f2bf(v.w);
    ((ushort4*)Ab)[idx] = h;
  }

  // --- labels ---
  if (idx < NQ) {
    int d = (idx - ptr) & (NQ - 1);
    int v = (d < NBATCH) ? labels[d] : ql[idx];
    out[1 + NFEAT + idx] = (float)v;
  }

  if (idx < NBATCH) flag[idx] = 0;
  if (idx == 0) {
    out[0] = 0.0f;
    out[1 + NFEAT + NQ] = (float)((ptr + NBATCH) & (NQ - 1));
  }
}

// ---------------------------------------------------------------------------
// 1. bf16 filter GEMM, double-buffered LDS, 2-phase prefetch.
//    LDS bank swizzle (T2 variant for global_load_lds): source address is
//    pre-permuted per lane so slot s=g*64+l holds (row=g*16+(l>>2),
//    kchunk=(l&3)^((l>>3)&3)); reads use fqx = fq ^ ((fr>>1)&3) -> each
//    16-lane b128 phase spans all 32 banks (was 8-way conflict).
// ---------------------------------------------------------------------------
__global__ __launch_bounds__(256) void gemm_mfma(
    const u16* __restrict__ A, const u16* __restrict__ B,
    unsigned* __restrict__ cand, int* __restrict__ cnt2,
    int* __restrict__ flag, int SLOT)
{
  __shared__ u16 sA[2][GM][GK];
  __shared__ u16 sB[2][GM][GK];
  __shared__ int lcnt[GM];

  const int tid  = threadIdx.x;
  const int wave = tid >> 6, lane = tid & 63;
  const int d  = blockIdx.x;
  const int bm = (d >> 3) & 3;
  const int bn = (d & 7) | ((d >> 5) << 3);

  for (int i = tid; i < GM; i += 256) lcnt[i] = 0;   // visible after 1st barrier

  // staging roles: waves 0,1 -> A halves; waves 2,3 -> B halves
  const u16* srcBase = ((wave < 2) ? (A + (size_t)bm * GM * DIM)
                                   : (B + (size_t)bn * GM * DIM))
                       + (size_t)(wave & 1) * 64 * DIM;
  const int kx = ((lane & 3) ^ ((lane >> 3) & 3)) * 8;  // swizzled k-chunk (u16)
  const u16* src = srcBase + (lane >> 2) * DIM + kx;
  u16* dst0 = ((wave < 2) ? &sA[0][0][0] : &sB[0][0][0]) + (wave & 1) * 64 * GK;
  u16* dst1 = ((wave < 2) ? &sA[1][0][0] : &sB[1][0][0]) + (wave & 1) * 64 * GK;

  const int wm = (wave & 1) * 64, wn = (wave >> 1) * 64;
  const int fr = lane & 15;
  const int fq = lane >> 4;
  const int fqx = fq ^ ((fr >> 1) & 3);   // swizzled read chunk

  f32x4 acc[4][4] = {};

  // prologue: stage tile 0 into buf 0
  {
    const u16* s = src;
#pragma unroll
    for (int g = 0; g < 4; ++g)
      load_lds16(s + g * 16 * DIM, dst0 + g * 512);
  }
  __syncthreads();

  for (int t = 0; t < KSTEPS; ++t) {
    const int cur = t & 1;
    if (t + 1 < KSTEPS) {        // issue next tile's loads BEFORE compute
      const u16* s = src + (t + 1) * GK;
      u16* dl = cur ? dst0 : dst1;
#pragma unroll
      for (int g = 0; g < 4; ++g)
        load_lds16(s + g * 16 * DIM, dl + g * 512);
    }

    short8 a[4], b[4];
#pragma unroll
    for (int i = 0; i < 4; ++i) {
      a[i] = *(const short8*)&sA[cur][wm + i * 16 + fr][fqx * 8];
      b[i] = *(const short8*)&sB[cur][wn + i * 16 + fr][fqx * 8];
    }
#pragma unroll
    for (int i = 0; i < 4; ++i)
#pragma unroll
      for (int j = 0; j < 4; ++j)
        acc[i][j] = __builtin_amdgcn_mfma_f32_16x16x32_bf16(a[i], b[j], acc[i][j], 0, 0, 0);

    __syncthreads();             // drains vmcnt(0): next tile landed; reads of cur done
  }

  // epilogue: D row = fq*4+r (m side), col = fr (n side) [verified R2]
  const int lrow0 = wm + fq * 4;
  const int ccol  = bn * GM + wn + fr;
#pragma unroll
  for (int i = 0; i < 4; ++i)
#pragma unroll
    for (int j = 0; j < 4; ++j)
#pragma unroll
      for (int r = 0; r < 4; ++r) {
        float v = acc[i][j][r];
        if (v > TSELF) {
          int lr  = lrow0 + i * 16 + r;
          int col = ccol + j * 16;
          int p = atomicAdd(&lcnt[lr], 1);
          if (p < SLOT)
            cand[((size_t)(bm * GM + lr) * NTN + bn) * SLOT + p] = (unsigned)col;
          else
            flag[bm * GM + lr] = 1;
        }
      }
  __syncthreads();
  if (tid < GM) {
    int c = lcnt[tid];
    cnt2[(size_t)(bm * GM + tid) * NTN + bn] = c < SLOT ? c : SLOT;
  }
}

// ---------------------------------------------------------------------------
// 2. select: gather candidate columns, wave-per-candidate EXACT f32 dot
//    recompute (coalesced 1KB row loads + butterfly reduce), sort-free
//    histogram selection + O(mb^2) boundary-bin ranking + vote.
//    Checked guard (BGUARD) makes the bf16 filter provably conservative;
//    inline exact full-recompute fallback otherwise.
// ---------------------------------------------------------------------------
#define NBSEL 2048
#define CCAP  2048
#define MBCAP 256
#define NT    512
#define NW    (NT / 64)

__global__ __launch_bounds__(NT) void select_kernel(
    const unsigned* __restrict__ cand, const int* __restrict__ cnt2,
    const int* __restrict__ flag, const int* __restrict__ labels,
    const int* __restrict__ qlab, const float* __restrict__ qf,
    const float* __restrict__ feat, float* __restrict__ out,
    float inv_n, int SLOT)
{
  __shared__ int   hist[NBSEL];
  __shared__ int   seg[NT];
  __shared__ float candV[CCAP];
  __shared__ int   candI[CCAP];
  __shared__ float votes[NCLS];
  __shared__ u64   bk[MBCAP];
  __shared__ float frow[DIM];
  __shared__ int   s_b, s_cnt, s_hi, s_mb;
  __shared__ u64   s_best;

  const int tid = threadIdx.x;
  const int row = blockIdx.x;
  const int wv = tid >> 6, ln = tid & 63;

  bool fb = (flag[row] != 0);           // block-uniform

  if (tid < DIM) frow[tid] = feat[(size_t)row * DIM + tid];
  for (int i = tid; i < NBSEL; i += NT) hist[i] = 0;
  for (int c = tid; c < NCLS; c += NT) votes[c] = 0.0f;
  if (tid == 0) { s_b = 0; s_cnt = 0; s_hi = 0; s_mb = 0; s_best = 0ull; }
  __syncthreads();

  if (!fb) {
    // ---- gather candidate columns from slotted lists ----
    const int*      rowcnt  = cnt2 + (size_t)row * NTN;
    const unsigned* rowcand = cand + (size_t)row * NTN * SLOT;
    for (int t = tid; t < NTN; t += NT) {
      int c = rowcnt[t];
      if (c > 0) {
        int p = atomicAdd(&s_cnt, c);
        for (int k = 0; k < c; ++k)
          if (p + k < CCAP) candI[p + k] = (int)rowcand[(size_t)t * SLOT + k];
      }
    }
    __syncthreads();
    const int n = s_cnt;
    if (n < KNN || n > CCAP) fb = true;
    else {
      // ---- wave-per-candidate exact f32 recompute (coalesced) ----
      const float4 fa = ((const float4*)frow)[ln];   // 64 lanes cover the row
      for (int i = wv; i < n; i += NW) {
        const float4* qr = (const float4*)(qf + (size_t)candI[i] * DIM);
        float4 b = qr[ln];
        float p = fmaf(fa.w, b.w, fmaf(fa.z, b.z, fmaf(fa.y, b.y, fa.x * b.x)));
#pragma unroll
        for (int off = 32; off > 0; off >>= 1) p += __shfl_xor(p, off, 64);
        if (ln == 0) candV[i] = p;
      }
      __syncthreads();

      // ---- histogram over (TSELH, ~1] ----
      const float SSCALE = (float)NBSEL / (1.001f - TSELH);
      for (int i = tid; i < n; i += NT) {
        int b = (int)((candV[i] - TSELH) * SSCALE);
        b = b < 0 ? 0 : (b > NBSEL - 1 ? NBSEL - 1 : b);
        atomicAdd(&hist[b], 1);
      }
      __syncthreads();
      { int s = 0;
#pragma unroll
        for (int i = 0; i < NBSEL / NT; ++i) s += hist[tid * (NBSEL / NT) + i];
        seg[tid] = s; }
      __syncthreads();
      for (int off = 1; off < NT; off <<= 1) {
        int t = (tid + off < NT) ? seg[tid + off] : 0;
        __syncthreads();
        seg[tid] += t;
        __syncthreads();
      }
      { int run = (tid < NT - 1) ? seg[tid + 1] : 0;
        for (int i = tid * (NBSEL / NT) + NBSEL / NT - 1;
             i >= tid * (NBSEL / NT); --i) {
          run += hist[i];
          if (run >= KNN) { atomicMax(&s_b, i); break; }
        } }
      __syncthreads();
      const int bstar = s_b;

      if (bstar < BGUARD) fb = true;   // filter-safety not provable -> exact path
      else {
        // ---- one pass: vote bins > b*, collect bin-b* elements ----
        for (int i = tid; i < n; i += NT) {
          float v = candV[i];
          int b = (int)((v - TSELH) * SSCALE);
          b = b < 0 ? 0 : (b > NBSEL - 1 ? NBSEL - 1 : b);
          if (b > bstar) {
            atomicAdd(&s_hi, 1);
            atomicAdd(&votes[qlab[candI[i]]], expf(v * (1.0f / 0.07f)));
          } else if (b == bstar) {
            int p = atomicAdd(&s_mb, 1);
            if (p < MBCAP)
              bk[p] = ((u64)__float_as_uint(v) << 32) |
                      (u64)(0xFFFFFFFFu - (unsigned)candI[i]);
          }
        }
        __syncthreads();
        const int mb = s_mb;
        if (mb > MBCAP) fb = true;   // fallback re-zeroes votes, so safe
        else {
          const int need = KNN - s_hi;   // 1 <= need <= mb by b* construction
          for (int e = tid; e < mb; e += NT) {
            u64 ke = bk[e];
            int rank = 0;
            for (int j = 0; j < mb; ++j) rank += (bk[j] > ke);
            if (rank < need) {
              float v = __uint_as_float((unsigned)(ke >> 32));
              int col = (int)(0xFFFFFFFFu - (unsigned)(ke & 0xFFFFFFFFull));
              atomicAdd(&votes[qlab[col]], expf(v * (1.0f / 0.07f)));
            }
          }
          __syncthreads();
        }
      }
    }
  }

  if (fb) {
    // ---- exact f32 recompute + selection over all NQ (guard path) ----
    for (int i = tid; i < NBSEL; i += NT) hist[i] = 0;
    if (tid == 0) { s_b = 0; s_cnt = 0; }
    __syncthreads();

    for (int q = tid; q < NQ; q += NT) {
      const float4* qr = (const float4*)(qf + (size_t)q * DIM);
      const float4* fr = (const float4*)frow;
      float s = 0.0f;
#pragma unroll
      for (int t = 0; t < DIM / 4; ++t) {
        float4 a = fr[t], b = qr[t];
        s = fmaf(a.x, b.x, s); s = fmaf(a.y, b.y, s);
        s = fmaf(a.z, b.z, s); s = fmaf(a.w, b.w, s);
      }
      int bin = (int)((s + 1.0f) * (NBSEL * 0.5f));
      bin = bin < 0 ? 0 : (bin > NBSEL - 1 ? NBSEL - 1 : bin);
      atomicAdd(&hist[bin], 1);
    }
    __syncthreads();

    { int s = 0;
#pragma unroll
      for (int i = 0; i < NBSEL / NT; ++i) s += hist[tid * (NBSEL / NT) + i];
      seg[tid] = s; }
    __syncthreads();
    for (int off = 1; off < NT; off <<= 1) {
      int t = (tid + off < NT) ? seg[tid + off] : 0;
      __syncthreads();
      seg[tid] += t;
      __syncthreads();
    }
    { int run = (tid < NT - 1) ? seg[tid + 1] : 0;
      for (int i = tid * (NBSEL / NT) + NBSEL / NT - 1;
           i >= tid * (NBSEL / NT); --i) {
        run += hist[i];
        if (run >= KNN) { atomicMax(&s_b, i); break; }
      } }
    __syncthreads();
    const int bstar = s_b;

    for (int q = tid; q < NQ; q += NT) {
      const float4* qr = (const float4*)(qf + (size_t)q * DIM);
      const float4* fr = (const float4*)frow;
      float s = 0.0f;
#pragma unroll
      for (int t = 0; t < DIM / 4; ++t) {
        float4 a = fr[t], b = qr[t];
        s = fmaf(a.x, b.x, s); s = fmaf(a.y, b.y, s);
        s = fmaf(a.z, b.z, s); s = fmaf(a.w, b.w, s);
      }
      int bin = (int)((s + 1.0f) * (NBSEL * 0.5f));
      bin = bin < 0 ? 0 : (bin > NBSEL - 1 ? NBSEL - 1 : bin);
      if (bin >= bstar) {
        int p = atomicAdd(&s_cnt, 1);
        if (p < CCAP) { candV[p] = s; candI[p] = q; }
      }
    }
    __syncthreads();
    int m = s_cnt < CCAP ? s_cnt : CCAP;

    int P = 256; while (P < m) P <<= 1;
    for (int i = tid; i < P; i += NT)
      if (i >= m) { candV[i] = -INFINITY; candI[i] = 0x7fffffff; }
    __syncthreads();
    for (int k = 2; k <= P; k <<= 1) {
      for (int j = k >> 1; j > 0; j >>= 1) {
        for (int i = tid; i < P; i += NT) {
          int ixj = i ^ j;
          if (ixj > i) {
            float va = candV[i], vb = candV[ixj];
            int ia = candI[i], ib = candI[ixj];
            bool aFirst = (va > vb) || (va == vb && ia < ib);
            bool up = ((i & k) == 0);
            if (up ? !aFirst : aFirst) {
              candV[i] = vb; candV[ixj] = va;
              candI[i] = ib; candI[ixj] = ia;
            }
          }
        }
        __syncthreads();
      }
    }

    for (int c = tid; c < NCLS; c += NT) votes[c] = 0.0f;
    __syncthreads();
    for (int i = tid; i < KNN; i += NT)
      atomicAdd(&votes[qlab[candI[i]]], expf(candV[i] * (1.0f / 0.07f)));
    __syncthreads();
  }

  // ---- common argmax (lowest class index on tie) + accuracy ----
  u64 key = 0ull;
  for (int c = tid; c < NCLS; c += NT) {
    u64 k2 = ((u64)__float_as_uint(votes[c]) << 32) |
             (u64)(0xFFFFFFFFu - (unsigned)c);
    if (k2 > key) key = k2;
  }
  for (int off = 32; off > 0; off >>= 1) {
    u64 o = __shfl_down(key, off, 64);
    if (o > key) key = o;
  }
  if ((tid & 63) == 0) atomicMax(&s_best, key);
  __syncthreads();
  if (tid == 0) {
    int cls = (int)(0xFFFFFFFFu - (unsigned)(s_best & 0xFFFFFFFFull));
    if (cls == labels[row]) atomicAdd(out, inv_n);
  }
}

// ---------------------------------------------------------------------------
extern "C" void kernel_launch(void* const* d_in, const int* in_sizes, int n_in,
                              void* d_out, int out_size, void* d_ws, size_t ws_size,
                              hipStream_t stream)
{
  const float* features = (const float*)d_in[0];
  const int*   labels   = (const int*)d_in[1];
  const float* qfeat    = (const float*)d_in[2];
  const int*   qlab     = (const int*)d_in[3];
  const int*   qptr     = (const int*)d_in[4];
  float* out = (float*)d_out;

  int nbatch = in_sizes[0] / DIM;             // 512
  float inv_n = 1.0f / (float)nbatch;

  // ws layout: [B 32MB][cand][cnt2 1MB][flag 2KB][A 256KB]
  size_t bBytes = (size_t)NQ * DIM * 2;                 // 32 MiB
  size_t fixed  = bBytes + (size_t)NBATCH * NTN * 4 + NBATCH * 4 +
                  (size_t)NBATCH * DIM * 2;
  int SLOT = 16;
  while ((size_t)NBATCH * NTN * SLOT * 4 + fixed > ws_size && SLOT > 2) SLOT >>= 1;

  u16*      Bb   = (u16*)d_ws;
  unsigned* cand = (unsigned*)((char*)d_ws + bBytes);
  int*      cnt2 = (int*)((char*)cand + (size_t)NBATCH * NTN * SLOT * 4);
  int*      flagp = cnt2 + (size_t)NBATCH * NTN;
  u16*      Ab   = (u16*)(flagp + NBATCH);

  prep_copy_kernel<<<NQ * DIM / 4 / 256, 256, 0, stream>>>(
      features, labels, qfeat, qlab, qptr, Bb, Ab, flagp, out);

  gemm_mfma<<<(NBATCH / GM) * (NQ / GM), 256, 0, stream>>>(
      Ab, Bb, cand, cnt2, flagp, SLOT);

  select_kernel<<<nbatch, NT, 0, stream>>>(cand, cnt2, flagp, labels, qlab,
                                           qfeat, features, out, inv_n, SLOT);
}

// Round 4
// 206.464 us; speedup vs baseline: 1.1568x; 1.1568x over previous
//
#include <hip/hip_runtime.h>
#include <math.h>

// Problem constants
#define NQ     65536
#define DIM    256
#define NBATCH 512
#define KNN    200
#define NCLS   1000
#define TSELF  0.155f    // bf16-filter threshold (top-200 boundary ~0.171)
#define TSELH  0.150f    // histogram base for exact recomputed values
// bf16 dot err bound: |err| <= 2*2^-9*||a||*||b|| ~= 3.9e-3 (unit norms).
// Guard: selected boundary bin must have lower edge >= TSELF + 4.1e-3, i.e.
// bstar >= ceil((TSELF+0.0041-TSELH)/binw) = 22, else exact fallback.
#define BGUARD 22

#define GM  128
#define GK  32
#define NTN (NQ / GM)    // 512 bn tiles
#define KSTEPS (DIM / GK)

typedef unsigned short u16;
typedef unsigned long long u64;
typedef __attribute__((ext_vector_type(8))) short short8;
typedef __attribute__((ext_vector_type(4))) float f32x4;

// out layout: [0] accuracy | [1..1+NQ*DIM) features | [..+NQ) labels | [last] ptr

__device__ __forceinline__ u16 f2bf(float x) {
  unsigned u = __float_as_uint(x);
  return (u16)((u + 0x7FFFu + ((u >> 16) & 1u)) >> 16);
}
__device__ __forceinline__ void load_lds16(const void* g, void* l) {
  __builtin_amdgcn_global_load_lds(
      (const __attribute__((address_space(1))) unsigned int*)g,
      (__attribute__((address_space(3))) unsigned int*)l, 16, 0, 0);
}
// out+1 is 4B-aligned, ≡4 (mod 16): dword, dwordx2 (8-aligned), dword
__device__ __forceinline__ void store_f4u(float* p, float4 v) {
  p[0] = v.x;
  *(float2*)(p + 1) = make_float2(v.y, v.z);
  p[3] = v.w;
}

// ---------------------------------------------------------------------------
// 0. fused prep + queue-update copy. Reads qf ONCE; writes out features
//    (with the 512 replaced rows), out labels, ptr, bf16 B (queue) and
//    bf16 A (batch), zeroes flag[] and accuracy.
// ---------------------------------------------------------------------------
__global__ __launch_bounds__(256) void prep_copy_kernel(
    const float* __restrict__ feat, const int* __restrict__ labels,
    const float* __restrict__ qf, const int* __restrict__ ql,
    const int* __restrict__ qptr,
    u16* __restrict__ Bb, u16* __restrict__ Ab,
    int* __restrict__ flag, float* __restrict__ out)
{
  const int idx = blockIdx.x * 256 + threadIdx.x;   // float4 index, < NQ*DIM/4
  const int ptr = qptr[0];
  const long long NFEAT = (long long)NQ * DIM;

  // --- queue features: out = old queue except rows (ptr..ptr+511)%NQ ---
  {
    float4 qv = ((const float4*)qf)[idx];
    int row = idx >> 6;                 // / (DIM/4)
    int c4  = idx & 63;
    int d = (row - ptr) & (NQ - 1);
    float4 ov = qv;
    if (d < NBATCH) ov = ((const float4*)feat)[d * 64 + c4];
    store_f4u(out + 1 + 4 * (long long)idx, ov);

    // --- B bf16 (ALWAYS old queue values) ---
    ushort4 h;
    h.x = f2bf(qv.x); h.y = f2bf(qv.y); h.z = f2bf(qv.z); h.w = f2bf(qv.w);
    ((ushort4*)Bb)[idx] = h;
  }

  // --- A bf16 (batch features) ---
  if (idx < NBATCH * DIM / 4) {
    float4 v = ((const float4*)feat)[idx];
    ushort4 h;
    h.x = f2bf(v.x); h.y = f2bf(v.y); h.z = f2bf(v.z); h.w = f2bf(v.w);
    ((ushort4*)Ab)[idx] = h;
  }

  // --- labels ---
  if (idx < NQ) {
    int d = (idx - ptr) & (NQ - 1);
    int v = (d < NBATCH) ? labels[d] : ql[idx];
    out[1 + NFEAT + idx] = (float)v;
  }

  if (idx < NBATCH) flag[idx] = 0;
  if (idx == 0) {
    out[0] = 0.0f;
    out[1 + NFEAT + NQ] = (float)((ptr + NBATCH) & (NQ - 1));
  }
}

// ---------------------------------------------------------------------------
// 1. bf16 filter GEMM, double-buffered LDS, 2-phase prefetch.
//    LDS bank swizzle (T2 variant for global_load_lds): source address is
//    pre-permuted per lane; reads use fqx = fq ^ ((fr>>1)&3).
// ---------------------------------------------------------------------------
__global__ __launch_bounds__(256) void gemm_mfma(
    const u16* __restrict__ A, const u16* __restrict__ B,
    unsigned* __restrict__ cand, int* __restrict__ cnt2,
    int* __restrict__ flag, int SLOT)
{
  __shared__ u16 sA[2][GM][GK];
  __shared__ u16 sB[2][GM][GK];
  __shared__ int lcnt[GM];

  const int tid  = threadIdx.x;
  const int wave = tid >> 6, lane = tid & 63;
  const int d  = blockIdx.x;
  const int bm = (d >> 3) & 3;
  const int bn = (d & 7) | ((d >> 5) << 3);

  for (int i = tid; i < GM; i += 256) lcnt[i] = 0;   // visible after 1st barrier

  // staging roles: waves 0,1 -> A halves; waves 2,3 -> B halves
  const u16* srcBase = ((wave < 2) ? (A + (size_t)bm * GM * DIM)
                                   : (B + (size_t)bn * GM * DIM))
                       + (size_t)(wave & 1) * 64 * DIM;
  const int kx = ((lane & 3) ^ ((lane >> 3) & 3)) * 8;  // swizzled k-chunk (u16)
  const u16* src = srcBase + (lane >> 2) * DIM + kx;
  u16* dst0 = ((wave < 2) ? &sA[0][0][0] : &sB[0][0][0]) + (wave & 1) * 64 * GK;
  u16* dst1 = ((wave < 2) ? &sA[1][0][0] : &sB[1][0][0]) + (wave & 1) * 64 * GK;

  const int wm = (wave & 1) * 64, wn = (wave >> 1) * 64;
  const int fr = lane & 15;
  const int fq = lane >> 4;
  const int fqx = fq ^ ((fr >> 1) & 3);   // swizzled read chunk

  f32x4 acc[4][4] = {};

  // prologue: stage tile 0 into buf 0
  {
    const u16* s = src;
#pragma unroll
    for (int g = 0; g < 4; ++g)
      load_lds16(s + g * 16 * DIM, dst0 + g * 512);
  }
  __syncthreads();

  for (int t = 0; t < KSTEPS; ++t) {
    const int cur = t & 1;
    if (t + 1 < KSTEPS) {        // issue next tile's loads BEFORE compute
      const u16* s = src + (t + 1) * GK;
      u16* dl = cur ? dst0 : dst1;
#pragma unroll
      for (int g = 0; g < 4; ++g)
        load_lds16(s + g * 16 * DIM, dl + g * 512);
    }

    short8 a[4], b[4];
#pragma unroll
    for (int i = 0; i < 4; ++i) {
      a[i] = *(const short8*)&sA[cur][wm + i * 16 + fr][fqx * 8];
      b[i] = *(const short8*)&sB[cur][wn + i * 16 + fr][fqx * 8];
    }
#pragma unroll
    for (int i = 0; i < 4; ++i)
#pragma unroll
      for (int j = 0; j < 4; ++j)
        acc[i][j] = __builtin_amdgcn_mfma_f32_16x16x32_bf16(a[i], b[j], acc[i][j], 0, 0, 0);

    __syncthreads();             // drains vmcnt(0): next tile landed; reads of cur done
  }

  // epilogue: D row = fq*4+r (m side), col = fr (n side) [verified R2]
  const int lrow0 = wm + fq * 4;
  const int ccol  = bn * GM + wn + fr;
#pragma unroll
  for (int i = 0; i < 4; ++i)
#pragma unroll
    for (int j = 0; j < 4; ++j)
#pragma unroll
      for (int r = 0; r < 4; ++r) {
        float v = acc[i][j][r];
        if (v > TSELF) {
          int lr  = lrow0 + i * 16 + r;
          int col = ccol + j * 16;
          int p = atomicAdd(&lcnt[lr], 1);
          if (p < SLOT)
            cand[((size_t)(bm * GM + lr) * NTN + bn) * SLOT + p] = (unsigned)col;
          else
            flag[bm * GM + lr] = 1;
        }
      }
  __syncthreads();
  if (tid < GM) {
    int c = lcnt[tid];
    cnt2[(size_t)(bm * GM + tid) * NTN + bn] = c < SLOT ? c : SLOT;
  }
}

// ---------------------------------------------------------------------------
// 2. select: gather candidate columns, 8-LANE-GROUP exact f32 dot recompute
//    (one 128B cache line per row per load instr; 8 candidates in flight per
//    wave; 8 independent unrolled loads per lane; 3-step shfl reduce),
//    sort-free histogram selection + O(mb^2) boundary-bin ranking + vote.
//    Checked guard (BGUARD) makes the bf16 filter provably conservative;
//    inline exact full-recompute fallback otherwise.
// ---------------------------------------------------------------------------
#define NBSEL 2048
#define CCAP  2048
#define MBCAP 256
#define NT    512
#define NG    (NT / 8)    // 8-lane groups per block

__global__ __launch_bounds__(NT) void select_kernel(
    const unsigned* __restrict__ cand, const int* __restrict__ cnt2,
    const int* __restrict__ flag, const int* __restrict__ labels,
    const int* __restrict__ qlab, const float* __restrict__ qf,
    const float* __restrict__ feat, float* __restrict__ out,
    float inv_n, int SLOT)
{
  __shared__ int   hist[NBSEL];
  __shared__ int   seg[NT];
  __shared__ float candV[CCAP];
  __shared__ int   candI[CCAP];
  __shared__ float votes[NCLS];
  __shared__ u64   bk[MBCAP];
  __shared__ float frow[DIM];
  __shared__ int   s_b, s_cnt, s_hi, s_mb;
  __shared__ u64   s_best;

  const int tid = threadIdx.x;
  const int row = blockIdx.x;

  bool fb = (flag[row] != 0);           // block-uniform

  if (tid < DIM) frow[tid] = feat[(size_t)row * DIM + tid];
  for (int i = tid; i < NBSEL; i += NT) hist[i] = 0;
  for (int c = tid; c < NCLS; c += NT) votes[c] = 0.0f;
  if (tid == 0) { s_b = 0; s_cnt = 0; s_hi = 0; s_mb = 0; s_best = 0ull; }
  __syncthreads();

  if (!fb) {
    // ---- gather candidate columns from slotted lists ----
    const int*      rowcnt  = cnt2 + (size_t)row * NTN;
    const unsigned* rowcand = cand + (size_t)row * NTN * SLOT;
    for (int t = tid; t < NTN; t += NT) {
      int c = rowcnt[t];
      if (c > 0) {
        int p = atomicAdd(&s_cnt, c);
        for (int k = 0; k < c; ++k)
          if (p + k < CCAP) candI[p + k] = (int)rowcand[(size_t)t * SLOT + k];
      }
    }
    __syncthreads();
    const int n = s_cnt;
    if (n < KNN || n > CCAP) fb = true;
    else {
      // ---- 8-lane-group exact f32 recompute ----
      const int sub = tid & 7;          // lane within group
      const int grp = tid >> 3;         // group id (0..NG-1)
      float4 fa[8];
#pragma unroll
      for (int it = 0; it < 8; ++it)
        fa[it] = ((const float4*)frow)[sub + it * 8];

      for (int i = grp; i < n; i += NG) {
        const float4* qr = (const float4*)(qf + (size_t)candI[i] * DIM);
        float p = 0.0f;
#pragma unroll
        for (int it = 0; it < 8; ++it) {
          float4 b = qr[sub + it * 8];  // 8 lanes = one 128B line of the row
          p = fmaf(fa[it].x, b.x, p); p = fmaf(fa[it].y, b.y, p);
          p = fmaf(fa[it].z, b.z, p); p = fmaf(fa[it].w, b.w, p);
        }
        p += __shfl_xor(p, 1, 64);
        p += __shfl_xor(p, 2, 64);
        p += __shfl_xor(p, 4, 64);
        if (sub == 0) candV[i] = p;
      }
      __syncthreads();

      // ---- histogram over (TSELH, ~1] ----
      const float SSCALE = (float)NBSEL / (1.001f - TSELH);
      for (int i = tid; i < n; i += NT) {
        int b = (int)((candV[i] - TSELH) * SSCALE);
        b = b < 0 ? 0 : (b > NBSEL - 1 ? NBSEL - 1 : b);
        atomicAdd(&hist[b], 1);
      }
      __syncthreads();
      { int s = 0;
#pragma unroll
        for (int i = 0; i < NBSEL / NT; ++i) s += hist[tid * (NBSEL / NT) + i];
        seg[tid] = s; }
      __syncthreads();
      for (int off = 1; off < NT; off <<= 1) {
        int t = (tid + off < NT) ? seg[tid + off] : 0;
        __syncthreads();
        seg[tid] += t;
        __syncthreads();
      }
      { int run = (tid < NT - 1) ? seg[tid + 1] : 0;
        for (int i = tid * (NBSEL / NT) + NBSEL / NT - 1;
             i >= tid * (NBSEL / NT); --i) {
          run += hist[i];
          if (run >= KNN) { atomicMax(&s_b, i); break; }
        } }
      __syncthreads();
      const int bstar = s_b;

      if (bstar < BGUARD) fb = true;   // filter-safety not provable -> exact path
      else {
        // ---- one pass: vote bins > b*, collect bin-b* elements ----
        for (int i = tid; i < n; i += NT) {
          float v = candV[i];
          int b = (int)((v - TSELH) * SSCALE);
          b = b < 0 ? 0 : (b > NBSEL - 1 ? NBSEL - 1 : b);
          if (b > bstar) {
            atomicAdd(&s_hi, 1);
            atomicAdd(&votes[qlab[candI[i]]], expf(v * (1.0f / 0.07f)));
          } else if (b == bstar) {
            int p = atomicAdd(&s_mb, 1);
            if (p < MBCAP)
              bk[p] = ((u64)__float_as_uint(v) << 32) |
                      (u64)(0xFFFFFFFFu - (unsigned)candI[i]);
          }
        }
        __syncthreads();
        const int mb = s_mb;
        if (mb > MBCAP) fb = true;   // fallback re-zeroes votes, so safe
        else {
          const int need = KNN - s_hi;   // 1 <= need <= mb by b* construction
          for (int e = tid; e < mb; e += NT) {
            u64 ke = bk[e];
            int rank = 0;
            for (int j = 0; j < mb; ++j) rank += (bk[j] > ke);
            if (rank < need) {
              float v = __uint_as_float((unsigned)(ke >> 32));
              int col = (int)(0xFFFFFFFFu - (unsigned)(ke & 0xFFFFFFFFull));
              atomicAdd(&votes[qlab[col]], expf(v * (1.0f / 0.07f)));
            }
          }
          __syncthreads();
        }
      }
    }
  }

  if (fb) {
    // ---- exact f32 recompute + selection over all NQ (guard path) ----
    for (int i = tid; i < NBSEL; i += NT) hist[i] = 0;
    if (tid == 0) { s_b = 0; s_cnt = 0; }
    __syncthreads();

    for (int q = tid; q < NQ; q += NT) {
      const float4* qr = (const float4*)(qf + (size_t)q * DIM);
      const float4* fr = (const float4*)frow;
      float s = 0.0f;
#pragma unroll
      for (int t = 0; t < DIM / 4; ++t) {
        float4 a = fr[t], b = qr[t];
        s = fmaf(a.x, b.x, s); s = fmaf(a.y, b.y, s);
        s = fmaf(a.z, b.z, s); s = fmaf(a.w, b.w, s);
      }
      int bin = (int)((s + 1.0f) * (NBSEL * 0.5f));
      bin = bin < 0 ? 0 : (bin > NBSEL - 1 ? NBSEL - 1 : bin);
      atomicAdd(&hist[bin], 1);
    }
    __syncthreads();

    { int s = 0;
#pragma unroll
      for (int i = 0; i < NBSEL / NT; ++i) s += hist[tid * (NBSEL / NT) + i];
      seg[tid] = s; }
    __syncthreads();
    for (int off = 1; off < NT; off <<= 1) {
      int t = (tid + off < NT) ? seg[tid + off] : 0;
      __syncthreads();
      seg[tid] += t;
      __syncthreads();
    }
    { int run = (tid < NT - 1) ? seg[tid + 1] : 0;
      for (int i = tid * (NBSEL / NT) + NBSEL / NT - 1;
           i >= tid * (NBSEL / NT); --i) {
        run += hist[i];
        if (run >= KNN) { atomicMax(&s_b, i); break; }
      } }
    __syncthreads();
    const int bstar = s_b;

    for (int q = tid; q < NQ; q += NT) {
      const float4* qr = (const float4*)(qf + (size_t)q * DIM);
      const float4* fr = (const float4*)frow;
      float s = 0.0f;
#pragma unroll
      for (int t = 0; t < DIM / 4; ++t) {
        float4 a = fr[t], b = qr[t];
        s = fmaf(a.x, b.x, s); s = fmaf(a.y, b.y, s);
        s = fmaf(a.z, b.z, s); s = fmaf(a.w, b.w, s);
      }
      int bin = (int)((s + 1.0f) * (NBSEL * 0.5f));
      bin = bin < 0 ? 0 : (bin > NBSEL - 1 ? NBSEL - 1 : bin);
      if (bin >= bstar) {
        int p = atomicAdd(&s_cnt, 1);
        if (p < CCAP) { candV[p] = s; candI[p] = q; }
      }
    }
    __syncthreads();
    int m = s_cnt < CCAP ? s_cnt : CCAP;

    int P = 256; while (P < m) P <<= 1;
    for (int i = tid; i < P; i += NT)
      if (i >= m) { candV[i] = -INFINITY; candI[i] = 0x7fffffff; }
    __syncthreads();
    for (int k = 2; k <= P; k <<= 1) {
      for (int j = k >> 1; j > 0; j >>= 1) {
        for (int i = tid; i < P; i += NT) {
          int ixj = i ^ j;
          if (ixj > i) {
            float va = candV[i], vb = candV[ixj];
            int ia = candI[i], ib = candI[ixj];
            bool aFirst = (va > vb) || (va == vb && ia < ib);
            bool up = ((i & k) == 0);
            if (up ? !aFirst : aFirst) {
              candV[i] = vb; candV[ixj] = va;
              candI[i] = ib; candI[ixj] = ia;
            }
          }
        }
        __syncthreads();
      }
    }

    for (int c = tid; c < NCLS; c += NT) votes[c] = 0.0f;
    __syncthreads();
    for (int i = tid; i < KNN; i += NT)
      atomicAdd(&votes[qlab[candI[i]]], expf(candV[i] * (1.0f / 0.07f)));
    __syncthreads();
  }

  // ---- common argmax (lowest class index on tie) + accuracy ----
  u64 key = 0ull;
  for (int c = tid; c < NCLS; c += NT) {
    u64 k2 = ((u64)__float_as_uint(votes[c]) << 32) |
             (u64)(0xFFFFFFFFu - (unsigned)c);
    if (k2 > key) key = k2;
  }
  for (int off = 32; off > 0; off >>= 1) {
    u64 o = __shfl_down(key, off, 64);
    if (o > key) key = o;
  }
  if ((tid & 63) == 0) atomicMax(&s_best, key);
  __syncthreads();
  if (tid == 0) {
    int cls = (int)(0xFFFFFFFFu - (unsigned)(s_best & 0xFFFFFFFFull));
    if (cls == labels[row]) atomicAdd(out, inv_n);
  }
}

// ---------------------------------------------------------------------------
extern "C" void kernel_launch(void* const* d_in, const int* in_sizes, int n_in,
                              void* d_out, int out_size, void* d_ws, size_t ws_size,
                              hipStream_t stream)
{
  const float* features = (const float*)d_in[0];
  const int*   labels   = (const int*)d_in[1];
  const float* qfeat    = (const float*)d_in[2];
  const int*   qlab     = (const int*)d_in[3];
  const int*   qptr     = (const int*)d_in[4];
  float* out = (float*)d_out;

  int nbatch = in_sizes[0] / DIM;             // 512
  float inv_n = 1.0f / (float)nbatch;

  // ws layout: [B 32MB][cand][cnt2 1MB][flag 2KB][A 256KB]
  size_t bBytes = (size_t)NQ * DIM * 2;                 // 32 MiB
  size_t fixed  = bBytes + (size_t)NBATCH * NTN * 4 + NBATCH * 4 +
                  (size_t)NBATCH * DIM * 2;
  int SLOT = 16;
  while ((size_t)NBATCH * NTN * SLOT * 4 + fixed > ws_size && SLOT > 2) SLOT >>= 1;

  u16*      Bb   = (u16*)d_ws;
  unsigned* cand = (unsigned*)((char*)d_ws + bBytes);
  int*      cnt2 = (int*)((char*)cand + (size_t)NBATCH * NTN * SLOT * 4);
  int*      flagp = cnt2 + (size_t)NBATCH * NTN;
  u16*      Ab   = (u16*)(flagp + NBATCH);

  prep_copy_kernel<<<NQ * DIM / 4 / 256, 256, 0, stream>>>(
      features, labels, qfeat, qlab, qptr, Bb, Ab, flagp, out);

  gemm_mfma<<<(NBATCH / GM) * (NQ / GM), 256, 0, stream>>>(
      Ab, Bb, cand, cnt2, flagp, SLOT);

  select_kernel<<<nbatch, NT, 0, stream>>>(cand, cnt2, flagp, labels, qlab,
                                           qfeat, features, out, inv_n, SLOT);
}

// Round 5
// 201.314 us; speedup vs baseline: 1.1863x; 1.0256x over previous
//
#include <hip/hip_runtime.h>
#include <math.h>

// Problem constants
#define NQ     65536
#define DIM    256
#define NBATCH 512
#define KNN    200
#define NCLS   1000
#define TSELF  0.155f    // bf16-filter threshold (top-200 boundary ~0.171)
#define TSELH  0.150f    // histogram base for exact recomputed values
// bf16 dot err bound: |err| <= 2*2^-9*||a||*||b|| ~= 3.9e-3 (unit norms).
// Guard: selected boundary bin must have lower edge >= TSELF + 4.1e-3, i.e.
// bstar >= ceil((TSELF+0.0041-TSELH)/binw) = 22, else exact fallback.
#define BGUARD 22

#define GM  128
#define GK  32
#define NTN (NQ / GM)    // 512 bn tiles
#define KSTEPS (DIM / GK)

typedef unsigned short u16;
typedef unsigned long long u64;
typedef __attribute__((ext_vector_type(8))) short short8;
typedef __attribute__((ext_vector_type(4))) float f32x4;

// out layout: [0] accuracy | [1..1+NQ*DIM) features | [..+NQ) labels | [last] ptr

__device__ __forceinline__ u16 f2bf(float x) {
  unsigned u = __float_as_uint(x);
  return (u16)((u + 0x7FFFu + ((u >> 16) & 1u)) >> 16);
}
__device__ __forceinline__ void load_lds16(const void* g, void* l) {
  __builtin_amdgcn_global_load_lds(
      (const __attribute__((address_space(1))) unsigned int*)g,
      (__attribute__((address_space(3))) unsigned int*)l, 16, 0, 0);
}
// out+1 is 4B-aligned, ≡4 (mod 16): dword, dwordx2 (8-aligned), dword
__device__ __forceinline__ void store_f4u(float* p, float4 v) {
  p[0] = v.x;
  *(float2*)(p + 1) = make_float2(v.y, v.z);
  p[3] = v.w;
}

// ---------------------------------------------------------------------------
// 0. fused prep + queue-update copy. Reads qf ONCE; writes out features
//    (with the 512 replaced rows), out labels, ptr, bf16 B (queue) and
//    bf16 A (batch), zeroes flag[] and accuracy.
// ---------------------------------------------------------------------------
__global__ __launch_bounds__(256) void prep_copy_kernel(
    const float* __restrict__ feat, const int* __restrict__ labels,
    const float* __restrict__ qf, const int* __restrict__ ql,
    const int* __restrict__ qptr,
    u16* __restrict__ Bb, u16* __restrict__ Ab,
    int* __restrict__ flag, float* __restrict__ out)
{
  const int idx = blockIdx.x * 256 + threadIdx.x;   // float4 index, < NQ*DIM/4
  const int ptr = qptr[0];
  const long long NFEAT = (long long)NQ * DIM;

  // --- queue features: out = old queue except rows (ptr..ptr+511)%NQ ---
  {
    float4 qv = ((const float4*)qf)[idx];
    int row = idx >> 6;                 // / (DIM/4)
    int c4  = idx & 63;
    int d = (row - ptr) & (NQ - 1);
    float4 ov = qv;
    if (d < NBATCH) ov = ((const float4*)feat)[d * 64 + c4];
    store_f4u(out + 1 + 4 * (long long)idx, ov);

    // --- B bf16 (ALWAYS old queue values) ---
    ushort4 h;
    h.x = f2bf(qv.x); h.y = f2bf(qv.y); h.z = f2bf(qv.z); h.w = f2bf(qv.w);
    ((ushort4*)Bb)[idx] = h;
  }

  // --- A bf16 (batch features) ---
  if (idx < NBATCH * DIM / 4) {
    float4 v = ((const float4*)feat)[idx];
    ushort4 h;
    h.x = f2bf(v.x); h.y = f2bf(v.y); h.z = f2bf(v.z); h.w = f2bf(v.w);
    ((ushort4*)Ab)[idx] = h;
  }

  // --- labels ---
  if (idx < NQ) {
    int d = (idx - ptr) & (NQ - 1);
    int v = (d < NBATCH) ? labels[d] : ql[idx];
    out[1 + NFEAT + idx] = (float)v;
  }

  if (idx < NBATCH) flag[idx] = 0;
  if (idx == 0) {
    out[0] = 0.0f;
    out[1 + NFEAT + NQ] = (float)((ptr + NBATCH) & (NQ - 1));
  }
}

// ---------------------------------------------------------------------------
// 1. bf16 filter GEMM, double-buffered LDS, 2-phase prefetch.
//    LDS bank swizzle (T2 variant for global_load_lds): source address is
//    pre-permuted per lane; reads use fqx = fq ^ ((fr>>1)&3).
// ---------------------------------------------------------------------------
__global__ __launch_bounds__(256) void gemm_mfma(
    const u16* __restrict__ A, const u16* __restrict__ B,
    unsigned* __restrict__ cand, int* __restrict__ cnt2,
    int* __restrict__ flag, int SLOT)
{
  __shared__ u16 sA[2][GM][GK];
  __shared__ u16 sB[2][GM][GK];
  __shared__ int lcnt[GM];

  const int tid  = threadIdx.x;
  const int wave = tid >> 6, lane = tid & 63;
  const int d  = blockIdx.x;
  const int bm = (d >> 3) & 3;
  const int bn = (d & 7) | ((d >> 5) << 3);

  for (int i = tid; i < GM; i += 256) lcnt[i] = 0;   // visible after 1st barrier

  // staging roles: waves 0,1 -> A halves; waves 2,3 -> B halves
  const u16* srcBase = ((wave < 2) ? (A + (size_t)bm * GM * DIM)
                                   : (B + (size_t)bn * GM * DIM))
                       + (size_t)(wave & 1) * 64 * DIM;
  const int kx = ((lane & 3) ^ ((lane >> 3) & 3)) * 8;  // swizzled k-chunk (u16)
  const u16* src = srcBase + (lane >> 2) * DIM + kx;
  u16* dst0 = ((wave < 2) ? &sA[0][0][0] : &sB[0][0][0]) + (wave & 1) * 64 * GK;
  u16* dst1 = ((wave < 2) ? &sA[1][0][0] : &sB[1][0][0]) + (wave & 1) * 64 * GK;

  const int wm = (wave & 1) * 64, wn = (wave >> 1) * 64;
  const int fr = lane & 15;
  const int fq = lane >> 4;
  const int fqx = fq ^ ((fr >> 1) & 3);   // swizzled read chunk

  f32x4 acc[4][4] = {};

  // prologue: stage tile 0 into buf 0
  {
    const u16* s = src;
#pragma unroll
    for (int g = 0; g < 4; ++g)
      load_lds16(s + g * 16 * DIM, dst0 + g * 512);
  }
  __syncthreads();

  for (int t = 0; t < KSTEPS; ++t) {
    const int cur = t & 1;
    if (t + 1 < KSTEPS) {        // issue next tile's loads BEFORE compute
      const u16* s = src + (t + 1) * GK;
      u16* dl = cur ? dst0 : dst1;
#pragma unroll
      for (int g = 0; g < 4; ++g)
        load_lds16(s + g * 16 * DIM, dl + g * 512);
    }

    short8 a[4], b[4];
#pragma unroll
    for (int i = 0; i < 4; ++i) {
      a[i] = *(const short8*)&sA[cur][wm + i * 16 + fr][fqx * 8];
      b[i] = *(const short8*)&sB[cur][wn + i * 16 + fr][fqx * 8];
    }
#pragma unroll
    for (int i = 0; i < 4; ++i)
#pragma unroll
      for (int j = 0; j < 4; ++j)
        acc[i][j] = __builtin_amdgcn_mfma_f32_16x16x32_bf16(a[i], b[j], acc[i][j], 0, 0, 0);

    __syncthreads();             // drains vmcnt(0): next tile landed; reads of cur done
  }

  // epilogue: D row = fq*4+r (m side), col = fr (n side) [verified R2]
  const int lrow0 = wm + fq * 4;
  const int ccol  = bn * GM + wn + fr;
#pragma unroll
  for (int i = 0; i < 4; ++i)
#pragma unroll
    for (int j = 0; j < 4; ++j)
#pragma unroll
      for (int r = 0; r < 4; ++r) {
        float v = acc[i][j][r];
        if (v > TSELF) {
          int lr  = lrow0 + i * 16 + r;
          int col = ccol + j * 16;
          int p = atomicAdd(&lcnt[lr], 1);
          if (p < SLOT)
            cand[((size_t)(bm * GM + lr) * NTN + bn) * SLOT + p] = (unsigned)col;
          else
            flag[bm * GM + lr] = 1;
        }
      }
  __syncthreads();
  if (tid < GM) {
    int c = lcnt[tid];
    cnt2[(size_t)(bm * GM + tid) * NTN + bn] = c < SLOT ? c : SLOT;
  }
}

// ---------------------------------------------------------------------------
// 2. select: gather candidate columns, 8-lane-group exact f32 dot recompute
//    with a MANUAL 2-DEEP PIPELINE (next candidate's 8 line-loads issued
//    before current candidate's reduce -> counted vmcnt, 2x lines in
//    flight), sort-free histogram selection + O(mb^2) boundary-bin ranking
//    + vote. frow is consumed from LDS inside the FMA loop (8-lane
//    broadcast, conflict-free) to keep VGPR <= 128 (2 blocks/CU).
//    Checked guard (BGUARD) makes the bf16 filter provably conservative;
//    inline exact full-recompute fallback otherwise.
// ---------------------------------------------------------------------------
#define NBSEL 2048
#define CCAP  2048
#define MBCAP 256
#define NT    512
#define NG    (NT / 8)    // 8-lane groups per block

__global__ __launch_bounds__(NT, 4) void select_kernel(
    const unsigned* __restrict__ cand, const int* __restrict__ cnt2,
    const int* __restrict__ flag, const int* __restrict__ labels,
    const int* __restrict__ qlab, const float* __restrict__ qf,
    const float* __restrict__ feat, float* __restrict__ out,
    float inv_n, int SLOT)
{
  __shared__ int   hist[NBSEL];
  __shared__ int   seg[NT];
  __shared__ float candV[CCAP];
  __shared__ int   candI[CCAP];
  __shared__ float votes[NCLS];
  __shared__ u64   bk[MBCAP];
  __shared__ float frow[DIM];
  __shared__ int   s_b, s_cnt, s_hi, s_mb;
  __shared__ u64   s_best;

  const int tid = threadIdx.x;
  const int row = blockIdx.x;

  bool fb = (flag[row] != 0);           // block-uniform

  if (tid < DIM) frow[tid] = feat[(size_t)row * DIM + tid];
  for (int i = tid; i < NBSEL; i += NT) hist[i] = 0;
  for (int c = tid; c < NCLS; c += NT) votes[c] = 0.0f;
  if (tid == 0) { s_b = 0; s_cnt = 0; s_hi = 0; s_mb = 0; s_best = 0ull; }
  __syncthreads();

  if (!fb) {
    // ---- gather candidate columns from slotted lists ----
    const int*      rowcnt  = cnt2 + (size_t)row * NTN;
    const unsigned* rowcand = cand + (size_t)row * NTN * SLOT;
    for (int t = tid; t < NTN; t += NT) {
      int c = rowcnt[t];
      if (c > 0) {
        int p = atomicAdd(&s_cnt, c);
        for (int k = 0; k < c; ++k)
          if (p + k < CCAP) candI[p + k] = (int)rowcand[(size_t)t * SLOT + k];
      }
    }
    __syncthreads();
    const int n = s_cnt;
    if (n < KNN || n > CCAP) fb = true;
    else {
      // ---- 8-lane-group exact f32 recompute, 2-deep pipelined ----
      const int sub = tid & 7;          // lane within group
      const int grp = tid >> 3;         // group id (0..NG-1)
      const float4* fr4 = (const float4*)frow;

      float4 b0[8];
      if (grp < n) {
        const float4* qr = (const float4*)(qf + (size_t)candI[grp] * DIM);
#pragma unroll
        for (int it = 0; it < 8; ++it) b0[it] = qr[sub + it * 8];
      }
      for (int i = grp; i < n; i += NG) {
        const int j = i + NG;
        float4 b1[8];
        if (j < n) {
          const float4* qr = (const float4*)(qf + (size_t)candI[j] * DIM);
#pragma unroll
          for (int it = 0; it < 8; ++it) b1[it] = qr[sub + it * 8];
        }
        float p = 0.0f;
#pragma unroll
        for (int it = 0; it < 8; ++it) {
          float4 a = fr4[sub + it * 8];   // LDS broadcast read
          p = fmaf(a.x, b0[it].x, p); p = fmaf(a.y, b0[it].y, p);
          p = fmaf(a.z, b0[it].z, p); p = fmaf(a.w, b0[it].w, p);
        }
        p += __shfl_xor(p, 1, 64);
        p += __shfl_xor(p, 2, 64);
        p += __shfl_xor(p, 4, 64);
        if (sub == 0) candV[i] = p;
#pragma unroll
        for (int it = 0; it < 8; ++it) b0[it] = b1[it];  // static rotate
      }
      __syncthreads();

      // ---- histogram over (TSELH, ~1] ----
      const float SSCALE = (float)NBSEL / (1.001f - TSELH);
      for (int i = tid; i < n; i += NT) {
        int b = (int)((candV[i] - TSELH) * SSCALE);
        b = b < 0 ? 0 : (b > NBSEL - 1 ? NBSEL - 1 : b);
        atomicAdd(&hist[b], 1);
      }
      __syncthreads();
      { int s = 0;
#pragma unroll
        for (int i = 0; i < NBSEL / NT; ++i) s += hist[tid * (NBSEL / NT) + i];
        seg[tid] = s; }
      __syncthreads();
      for (int off = 1; off < NT; off <<= 1) {
        int t = (tid + off < NT) ? seg[tid + off] : 0;
        __syncthreads();
        seg[tid] += t;
        __syncthreads();
      }
      { int run = (tid < NT - 1) ? seg[tid + 1] : 0;
        for (int i = tid * (NBSEL / NT) + NBSEL / NT - 1;
             i >= tid * (NBSEL / NT); --i) {
          run += hist[i];
          if (run >= KNN) { atomicMax(&s_b, i); break; }
        } }
      __syncthreads();
      const int bstar = s_b;

      if (bstar < BGUARD) fb = true;   // filter-safety not provable -> exact path
      else {
        // ---- one pass: vote bins > b*, collect bin-b* elements ----
        for (int i = tid; i < n; i += NT) {
          float v = candV[i];
          int b = (int)((v - TSELH) * SSCALE);
          b = b < 0 ? 0 : (b > NBSEL - 1 ? NBSEL - 1 : b);
          if (b > bstar) {
            atomicAdd(&s_hi, 1);
            atomicAdd(&votes[qlab[candI[i]]], expf(v * (1.0f / 0.07f)));
          } else if (b == bstar) {
            int p = atomicAdd(&s_mb, 1);
            if (p < MBCAP)
              bk[p] = ((u64)__float_as_uint(v) << 32) |
                      (u64)(0xFFFFFFFFu - (unsigned)candI[i]);
          }
        }
        __syncthreads();
        const int mb = s_mb;
        if (mb > MBCAP) fb = true;   // fallback re-zeroes votes, so safe
        else {
          const int need = KNN - s_hi;   // 1 <= need <= mb by b* construction
          for (int e = tid; e < mb; e += NT) {
            u64 ke = bk[e];
            int rank = 0;
            for (int j = 0; j < mb; ++j) rank += (bk[j] > ke);
            if (rank < need) {
              float v = __uint_as_float((unsigned)(ke >> 32));
              int col = (int)(0xFFFFFFFFu - (unsigned)(ke & 0xFFFFFFFFull));
              atomicAdd(&votes[qlab[col]], expf(v * (1.0f / 0.07f)));
            }
          }
          __syncthreads();
        }
      }
    }
  }

  if (fb) {
    // ---- exact f32 recompute + selection over all NQ (guard path) ----
    for (int i = tid; i < NBSEL; i += NT) hist[i] = 0;
    if (tid == 0) { s_b = 0; s_cnt = 0; }
    __syncthreads();

    for (int q = tid; q < NQ; q += NT) {
      const float4* qr = (const float4*)(qf + (size_t)q * DIM);
      const float4* fr = (const float4*)frow;
      float s = 0.0f;
#pragma unroll
      for (int t = 0; t < DIM / 4; ++t) {
        float4 a = fr[t], b = qr[t];
        s = fmaf(a.x, b.x, s); s = fmaf(a.y, b.y, s);
        s = fmaf(a.z, b.z, s); s = fmaf(a.w, b.w, s);
      }
      int bin = (int)((s + 1.0f) * (NBSEL * 0.5f));
      bin = bin < 0 ? 0 : (bin > NBSEL - 1 ? NBSEL - 1 : bin);
      atomicAdd(&hist[bin], 1);
    }
    __syncthreads();

    { int s = 0;
#pragma unroll
      for (int i = 0; i < NBSEL / NT; ++i) s += hist[tid * (NBSEL / NT) + i];
      seg[tid] = s; }
    __syncthreads();
    for (int off = 1; off < NT; off <<= 1) {
      int t = (tid + off < NT) ? seg[tid + off] : 0;
      __syncthreads();
      seg[tid] += t;
      __syncthreads();
    }
    { int run = (tid < NT - 1) ? seg[tid + 1] : 0;
      for (int i = tid * (NBSEL / NT) + NBSEL / NT - 1;
           i >= tid * (NBSEL / NT); --i) {
        run += hist[i];
        if (run >= KNN) { atomicMax(&s_b, i); break; }
      } }
    __syncthreads();
    const int bstar = s_b;

    for (int q = tid; q < NQ; q += NT) {
      const float4* qr = (const float4*)(qf + (size_t)q * DIM);
      const float4* fr = (const float4*)frow;
      float s = 0.0f;
#pragma unroll
      for (int t = 0; t < DIM / 4; ++t) {
        float4 a = fr[t], b = qr[t];
        s = fmaf(a.x, b.x, s); s = fmaf(a.y, b.y, s);
        s = fmaf(a.z, b.z, s); s = fmaf(a.w, b.w, s);
      }
      int bin = (int)((s + 1.0f) * (NBSEL * 0.5f));
      bin = bin < 0 ? 0 : (bin > NBSEL - 1 ? NBSEL - 1 : bin);
      if (bin >= bstar) {
        int p = atomicAdd(&s_cnt, 1);
        if (p < CCAP) { candV[p] = s; candI[p] = q; }
      }
    }
    __syncthreads();
    int m = s_cnt < CCAP ? s_cnt : CCAP;

    int P = 256; while (P < m) P <<= 1;
    for (int i = tid; i < P; i += NT)
      if (i >= m) { candV[i] = -INFINITY; candI[i] = 0x7fffffff; }
    __syncthreads();
    for (int k = 2; k <= P; k <<= 1) {
      for (int j = k >> 1; j > 0; j >>= 1) {
        for (int i = tid; i < P; i += NT) {
          int ixj = i ^ j;
          if (ixj > i) {
            float va = candV[i], vb = candV[ixj];
            int ia = candI[i], ib = candI[ixj];
            bool aFirst = (va > vb) || (va == vb && ia < ib);
            bool up = ((i & k) == 0);
            if (up ? !aFirst : aFirst) {
              candV[i] = vb; candV[ixj] = va;
              candI[i] = ib; candI[ixj] = ia;
            }
          }
        }
        __syncthreads();
      }
    }

    for (int c = tid; c < NCLS; c += NT) votes[c] = 0.0f;
    __syncthreads();
    for (int i = tid; i < KNN; i += NT)
      atomicAdd(&votes[qlab[candI[i]]], expf(candV[i] * (1.0f / 0.07f)));
    __syncthreads();
  }

  // ---- common argmax (lowest class index on tie) + accuracy ----
  u64 key = 0ull;
  for (int c = tid; c < NCLS; c += NT) {
    u64 k2 = ((u64)__float_as_uint(votes[c]) << 32) |
             (u64)(0xFFFFFFFFu - (unsigned)c);
    if (k2 > key) key = k2;
  }
  for (int off = 32; off > 0; off >>= 1) {
    u64 o = __shfl_down(key, off, 64);
    if (o > key) key = o;
  }
  if ((tid & 63) == 0) atomicMax(&s_best, key);
  __syncthreads();
  if (tid == 0) {
    int cls = (int)(0xFFFFFFFFu - (unsigned)(s_best & 0xFFFFFFFFull));
    if (cls == labels[row]) atomicAdd(out, inv_n);
  }
}

// ---------------------------------------------------------------------------
extern "C" void kernel_launch(void* const* d_in, const int* in_sizes, int n_in,
                              void* d_out, int out_size, void* d_ws, size_t ws_size,
                              hipStream_t stream)
{
  const float* features = (const float*)d_in[0];
  const int*   labels   = (const int*)d_in[1];
  const float* qfeat    = (const float*)d_in[2];
  const int*   qlab     = (const int*)d_in[3];
  const int*   qptr     = (const int*)d_in[4];
  float* out = (float*)d_out;

  int nbatch = in_sizes[0] / DIM;             // 512
  float inv_n = 1.0f / (float)nbatch;

  // ws layout: [B 32MB][cand][cnt2 1MB][flag 2KB][A 256KB]
  size_t bBytes = (size_t)NQ * DIM * 2;                 // 32 MiB
  size_t fixed  = bBytes + (size_t)NBATCH * NTN * 4 + NBATCH * 4 +
                  (size_t)NBATCH * DIM * 2;
  int SLOT = 16;
  while ((size_t)NBATCH * NTN * SLOT * 4 + fixed > ws_size && SLOT > 2) SLOT >>= 1;

  u16*      Bb   = (u16*)d_ws;
  unsigned* cand = (unsigned*)((char*)d_ws + bBytes);
  int*      cnt2 = (int*)((char*)cand + (size_t)NBATCH * NTN * SLOT * 4);
  int*      flagp = cnt2 + (size_t)NBATCH * NTN;
  u16*      Ab   = (u16*)(flagp + NBATCH);

  prep_copy_kernel<<<NQ * DIM / 4 / 256, 256, 0, stream>>>(
      features, labels, qfeat, qlab, qptr, Bb, Ab, flagp, out);

  gemm_mfma<<<(NBATCH / GM) * (NQ / GM), 256, 0, stream>>>(
      Ab, Bb, cand, cnt2, flagp, SLOT);

  select_kernel<<<nbatch, NT, 0, stream>>>(cand, cnt2, flagp, labels, qlab,
                                           qfeat, features, out, inv_n, SLOT);
}

// Round 6
// 200.905 us; speedup vs baseline: 1.1888x; 1.0020x over previous
//
#include <hip/hip_runtime.h>
#include <math.h>

// Problem constants
#define NQ     65536
#define DIM    256
#define NBATCH 512
#define KNN    200
#define NCLS   1000
#define TSELF  0.155f    // bf16-filter threshold (top-200 boundary ~0.171)
#define TSELH  0.150f    // histogram base
// bf16 dot err bound: |approx-exact| <= 2^-8*||a||*||b|| + f32 accum ~= 4.0e-3.
#define EPSF   0.0041f
// Guard: exact boundary bin must have lower edge >= TSELF + EPSF, i.e.
// bstar >= ceil((TSELF+0.0041-TSELH)/binw) = 22, else exact fallback.
#define BGUARD 22

#define GM  128
#define GK  32
#define NTN (NQ / GM)    // 512 bn tiles
#define KSTEPS (DIM / GK)

typedef unsigned short u16;
typedef unsigned long long u64;
typedef __attribute__((ext_vector_type(8))) short short8;
typedef __attribute__((ext_vector_type(4))) float f32x4;

// out layout: [0] accuracy | [1..1+NQ*DIM) features | [..+NQ) labels | [last] ptr

__device__ __forceinline__ u16 f2bf(float x) {
  unsigned u = __float_as_uint(x);
  return (u16)((u + 0x7FFFu + ((u >> 16) & 1u)) >> 16);
}
__device__ __forceinline__ void load_lds16(const void* g, void* l) {
  __builtin_amdgcn_global_load_lds(
      (const __attribute__((address_space(1))) unsigned int*)g,
      (__attribute__((address_space(3))) unsigned int*)l, 16, 0, 0);
}
// out+1 is 4B-aligned, ≡4 (mod 16): dword, dwordx2 (8-aligned), dword
__device__ __forceinline__ void store_f4u(float* p, float4 v) {
  p[0] = v.x;
  *(float2*)(p + 1) = make_float2(v.y, v.z);
  p[3] = v.w;
}

// ---------------------------------------------------------------------------
// 0. fused prep + queue-update copy.
// ---------------------------------------------------------------------------
__global__ __launch_bounds__(256) void prep_copy_kernel(
    const float* __restrict__ feat, const int* __restrict__ labels,
    const float* __restrict__ qf, const int* __restrict__ ql,
    const int* __restrict__ qptr,
    u16* __restrict__ Bb, u16* __restrict__ Ab,
    int* __restrict__ flag, float* __restrict__ out)
{
  const int idx = blockIdx.x * 256 + threadIdx.x;   // float4 index, < NQ*DIM/4
  const int ptr = qptr[0];
  const long long NFEAT = (long long)NQ * DIM;

  {
    float4 qv = ((const float4*)qf)[idx];
    int row = idx >> 6;                 // / (DIM/4)
    int c4  = idx & 63;
    int d = (row - ptr) & (NQ - 1);
    float4 ov = qv;
    if (d < NBATCH) ov = ((const float4*)feat)[d * 64 + c4];
    store_f4u(out + 1 + 4 * (long long)idx, ov);

    ushort4 h;
    h.x = f2bf(qv.x); h.y = f2bf(qv.y); h.z = f2bf(qv.z); h.w = f2bf(qv.w);
    ((ushort4*)Bb)[idx] = h;
  }

  if (idx < NBATCH * DIM / 4) {
    float4 v = ((const float4*)feat)[idx];
    ushort4 h;
    h.x = f2bf(v.x); h.y = f2bf(v.y); h.z = f2bf(v.z); h.w = f2bf(v.w);
    ((ushort4*)Ab)[idx] = h;
  }

  if (idx < NQ) {
    int d = (idx - ptr) & (NQ - 1);
    int v = (d < NBATCH) ? labels[d] : ql[idx];
    out[1 + NFEAT + idx] = (float)v;
  }

  if (idx < NBATCH) flag[idx] = 0;
  if (idx == 0) {
    out[0] = 0.0f;
    out[1 + NFEAT + NQ] = (float)((ptr + NBATCH) & (NQ - 1));
  }
}

// ---------------------------------------------------------------------------
// 1. bf16 filter GEMM, double-buffered LDS, 2-phase prefetch, bank swizzle.
//    Epilogue stores (approx value, col) as uint2 — approx guides select's
//    targeted exact recompute.
// ---------------------------------------------------------------------------
__global__ __launch_bounds__(256) void gemm_mfma(
    const u16* __restrict__ A, const u16* __restrict__ B,
    uint2* __restrict__ cand, int* __restrict__ cnt2,
    int* __restrict__ flag, int SLOT)
{
  __shared__ u16 sA[2][GM][GK];
  __shared__ u16 sB[2][GM][GK];
  __shared__ int lcnt[GM];

  const int tid  = threadIdx.x;
  const int wave = tid >> 6, lane = tid & 63;
  const int d  = blockIdx.x;
  const int bm = (d >> 3) & 3;
  const int bn = (d & 7) | ((d >> 5) << 3);

  for (int i = tid; i < GM; i += 256) lcnt[i] = 0;   // visible after 1st barrier

  const u16* srcBase = ((wave < 2) ? (A + (size_t)bm * GM * DIM)
                                   : (B + (size_t)bn * GM * DIM))
                       + (size_t)(wave & 1) * 64 * DIM;
  const int kx = ((lane & 3) ^ ((lane >> 3) & 3)) * 8;  // swizzled k-chunk (u16)
  const u16* src = srcBase + (lane >> 2) * DIM + kx;
  u16* dst0 = ((wave < 2) ? &sA[0][0][0] : &sB[0][0][0]) + (wave & 1) * 64 * GK;
  u16* dst1 = ((wave < 2) ? &sA[1][0][0] : &sB[1][0][0]) + (wave & 1) * 64 * GK;

  const int wm = (wave & 1) * 64, wn = (wave >> 1) * 64;
  const int fr = lane & 15;
  const int fq = lane >> 4;
  const int fqx = fq ^ ((fr >> 1) & 3);   // swizzled read chunk

  f32x4 acc[4][4] = {};

  {
    const u16* s = src;
#pragma unroll
    for (int g = 0; g < 4; ++g)
      load_lds16(s + g * 16 * DIM, dst0 + g * 512);
  }
  __syncthreads();

  for (int t = 0; t < KSTEPS; ++t) {
    const int cur = t & 1;
    if (t + 1 < KSTEPS) {        // issue next tile's loads BEFORE compute
      const u16* s = src + (t + 1) * GK;
      u16* dl = cur ? dst0 : dst1;
#pragma unroll
      for (int g = 0; g < 4; ++g)
        load_lds16(s + g * 16 * DIM, dl + g * 512);
    }

    short8 a[4], b[4];
#pragma unroll
    for (int i = 0; i < 4; ++i) {
      a[i] = *(const short8*)&sA[cur][wm + i * 16 + fr][fqx * 8];
      b[i] = *(const short8*)&sB[cur][wn + i * 16 + fr][fqx * 8];
    }
#pragma unroll
    for (int i = 0; i < 4; ++i)
#pragma unroll
      for (int j = 0; j < 4; ++j)
        acc[i][j] = __builtin_amdgcn_mfma_f32_16x16x32_bf16(a[i], b[j], acc[i][j], 0, 0, 0);

    __syncthreads();
  }

  // epilogue: D row = fq*4+r (m side), col = fr (n side)
  const int lrow0 = wm + fq * 4;
  const int ccol  = bn * GM + wn + fr;
#pragma unroll
  for (int i = 0; i < 4; ++i)
#pragma unroll
    for (int j = 0; j < 4; ++j)
#pragma unroll
      for (int r = 0; r < 4; ++r) {
        float v = acc[i][j][r];
        if (v > TSELF) {
          int lr  = lrow0 + i * 16 + r;
          int col = ccol + j * 16;
          int p = atomicAdd(&lcnt[lr], 1);
          if (p < SLOT)
            cand[((size_t)(bm * GM + lr) * NTN + bn) * SLOT + p] =
                make_uint2(__float_as_uint(v), (unsigned)col);
          else
            flag[bm * GM + lr] = 1;
        }
      }
  __syncthreads();
  if (tid < GM) {
    int c = lcnt[tid];
    cnt2[(size_t)(bm * GM + tid) * NTN + bn] = c < SLOT ? c : SLOT;
  }
}

// ---------------------------------------------------------------------------
// 2. select: gather (approx,col); approx histogram -> provisional boundary
//    b*_a; EXACT recompute only for candidates with approx >= edge(b*_a)-2eps
//    (provably contains true top-200); exact histogram + boundary-bin rank +
//    vote on exact values. Guards: BGUARD, list/cap overflows -> exact
//    full-recompute fallback.
// ---------------------------------------------------------------------------
#define NBSEL 2048
#define CCAP  2048
#define MBCAP 256
#define LCAP  1024
#define NT    512
#define NG    (NT / 8)    // 8-lane groups per block
#define BINW  ((1.001f - TSELH) / (float)NBSEL)

__global__ __launch_bounds__(NT, 4) void select_kernel(
    const uint2* __restrict__ cand, const int* __restrict__ cnt2,
    const int* __restrict__ flag, const int* __restrict__ labels,
    const int* __restrict__ qlab, const float* __restrict__ qf,
    const float* __restrict__ feat, float* __restrict__ out,
    float inv_n, int SLOT)
{
  __shared__ int   hist[NBSEL];
  __shared__ int   seg[NT];
  __shared__ float candV[CCAP];
  __shared__ int   candI[CCAP];
  __shared__ float votes[NCLS];
  __shared__ u64   bk[LCAP / 2];     // doubles as int list[LCAP] for compaction
  __shared__ float frow[DIM];
  __shared__ int   s_b, s_cnt, s_hi, s_mb;
  __shared__ u64   s_best;

  const int tid = threadIdx.x;
  const int row = blockIdx.x;

  bool fb = (flag[row] != 0);           // block-uniform

  if (tid < DIM) frow[tid] = feat[(size_t)row * DIM + tid];
  for (int i = tid; i < NBSEL; i += NT) hist[i] = 0;
  for (int c = tid; c < NCLS; c += NT) votes[c] = 0.0f;
  if (tid == 0) { s_b = 0; s_cnt = 0; s_hi = 0; s_mb = 0; s_best = 0ull; }
  __syncthreads();

  if (!fb) {
    // ---- gather (approx, col) from slotted lists ----
    const int*   rowcnt  = cnt2 + (size_t)row * NTN;
    const uint2* rowcand = cand + (size_t)row * NTN * SLOT;
    for (int t = tid; t < NTN; t += NT) {
      int c = rowcnt[t];
      if (c > 0) {
        int p = atomicAdd(&s_cnt, c);
        for (int k = 0; k < c; ++k) {
          if (p + k < CCAP) {
            uint2 e = rowcand[(size_t)t * SLOT + k];
            candV[p + k] = __uint_as_float(e.x);
            candI[p + k] = (int)e.y;
          }
        }
      }
    }
    __syncthreads();
    const int n = s_cnt;
    if (n < KNN || n > CCAP) fb = true;
    else {
      // ---- approx histogram over (TSELH, ~1] ----
      const float SSCALE = 1.0f / BINW;
      for (int i = tid; i < n; i += NT) {
        int b = (int)((candV[i] - TSELH) * SSCALE);
        b = b < 0 ? 0 : (b > NBSEL - 1 ? NBSEL - 1 : b);
        atomicAdd(&hist[b], 1);
      }
      __syncthreads();
      { int s = 0;
#pragma unroll
        for (int i = 0; i < NBSEL / NT; ++i) s += hist[tid * (NBSEL / NT) + i];
        seg[tid] = s; }
      __syncthreads();
      for (int off = 1; off < NT; off <<= 1) {
        int t = (tid + off < NT) ? seg[tid + off] : 0;
        __syncthreads();
        seg[tid] += t;
        __syncthreads();
      }
      { int run = (tid < NT - 1) ? seg[tid + 1] : 0;
        for (int i = tid * (NBSEL / NT) + NBSEL / NT - 1;
             i >= tid * (NBSEL / NT); --i) {
          run += hist[i];
          if (run >= KNN) { atomicMax(&s_b, i); break; }
        } }
      __syncthreads();
      const int bstarA = s_b;
      const float thresh = TSELH + (float)bstarA * BINW - 2.0f * EPSF;

      // ---- re-zero hist, compact recompute list ----
      int* lst = (int*)bk;
      for (int i = tid; i < NBSEL; i += NT) hist[i] = 0;
      if (tid == 0) s_b = 0;
      for (int i = tid; i < n; i += NT) {
        if (candV[i] >= thresh) {
          int p = atomicAdd(&s_mb, 1);
          if (p < LCAP) lst[p] = i;
        }
      }
      __syncthreads();
      const int nr = s_mb;
      if (nr > LCAP) fb = true;
      else {
        // ---- 8-lane-group exact recompute over list, 2-deep pipelined ----
        const int sub = tid & 7;
        const int grp = tid >> 3;
        const float4* fr4 = (const float4*)frow;

        float4 b0[8];
        if (grp < nr) {
          const float4* qr = (const float4*)(qf + (size_t)candI[lst[grp]] * DIM);
#pragma unroll
          for (int it = 0; it < 8; ++it) b0[it] = qr[sub + it * 8];
        }
        for (int k = grp; k < nr; k += NG) {
          const int kn = k + NG;
          float4 b1[8];
          if (kn < nr) {
            const float4* qr = (const float4*)(qf + (size_t)candI[lst[kn]] * DIM);
#pragma unroll
            for (int it = 0; it < 8; ++it) b1[it] = qr[sub + it * 8];
          }
          float p = 0.0f;
#pragma unroll
          for (int it = 0; it < 8; ++it) {
            float4 a = fr4[sub + it * 8];   // LDS broadcast read
            p = fmaf(a.x, b0[it].x, p); p = fmaf(a.y, b0[it].y, p);
            p = fmaf(a.z, b0[it].z, p); p = fmaf(a.w, b0[it].w, p);
          }
          p += __shfl_xor(p, 1, 64);
          p += __shfl_xor(p, 2, 64);
          p += __shfl_xor(p, 4, 64);
          if (sub == 0) candV[lst[k]] = p;   // exact overwrites approx
#pragma unroll
          for (int it = 0; it < 8; ++it) b0[it] = b1[it];  // static rotate
        }
        if (tid == 0) s_mb = 0;              // reuse for boundary collection
        __syncthreads();

        // ---- exact histogram (included = candV >= thresh) ----
        for (int i = tid; i < n; i += NT) {
          float v = candV[i];
          if (v >= thresh) {
            int b = (int)((v - TSELH) * SSCALE);
            b = b < 0 ? 0 : (b > NBSEL - 1 ? NBSEL - 1 : b);
            atomicAdd(&hist[b], 1);
          }
        }
        __syncthreads();
        { int s = 0;
#pragma unroll
          for (int i = 0; i < NBSEL / NT; ++i) s += hist[tid * (NBSEL / NT) + i];
          seg[tid] = s; }
        __syncthreads();
        for (int off = 1; off < NT; off <<= 1) {
          int t = (tid + off < NT) ? seg[tid + off] : 0;
          __syncthreads();
          seg[tid] += t;
          __syncthreads();
        }
        { int run = (tid < NT - 1) ? seg[tid + 1] : 0;
          for (int i = tid * (NBSEL / NT) + NBSEL / NT - 1;
               i >= tid * (NBSEL / NT); --i) {
            run += hist[i];
            if (run >= KNN) { atomicMax(&s_b, i); break; }
          } }
        __syncthreads();
        const int bstar = s_b;

        if (bstar < BGUARD) fb = true;   // filter-safety not provable
        else {
          // ---- vote bins > b*, collect bin-b* elements ----
          for (int i = tid; i < n; i += NT) {
            float v = candV[i];
            if (v < thresh) continue;
            int b = (int)((v - TSELH) * SSCALE);
            b = b < 0 ? 0 : (b > NBSEL - 1 ? NBSEL - 1 : b);
            if (b > bstar) {
              atomicAdd(&s_hi, 1);
              atomicAdd(&votes[qlab[candI[i]]], expf(v * (1.0f / 0.07f)));
            } else if (b == bstar) {
              int p = atomicAdd(&s_mb, 1);
              if (p < MBCAP)
                bk[p] = ((u64)__float_as_uint(v) << 32) |
                        (u64)(0xFFFFFFFFu - (unsigned)candI[i]);
            }
          }
          __syncthreads();
          const int mb = s_mb;
          if (mb > MBCAP) fb = true;   // fallback re-zeroes votes, so safe
          else {
            const int need = KNN - s_hi;   // 1 <= need <= mb by construction
            for (int e = tid; e < mb; e += NT) {
              u64 ke = bk[e];
              int rank = 0;
              for (int j = 0; j < mb; ++j) rank += (bk[j] > ke);
              if (rank < need) {
                float v = __uint_as_float((unsigned)(ke >> 32));
                int col = (int)(0xFFFFFFFFu - (unsigned)(ke & 0xFFFFFFFFull));
                atomicAdd(&votes[qlab[col]], expf(v * (1.0f / 0.07f)));
              }
            }
            __syncthreads();
          }
        }
      }
    }
  }

  if (fb) {
    // ---- exact f32 recompute + selection over all NQ (guard path) ----
    for (int i = tid; i < NBSEL; i += NT) hist[i] = 0;
    if (tid == 0) { s_b = 0; s_cnt = 0; }
    __syncthreads();

    for (int q = tid; q < NQ; q += NT) {
      const float4* qr = (const float4*)(qf + (size_t)q * DIM);
      const float4* fr = (const float4*)frow;
      float s = 0.0f;
#pragma unroll
      for (int t = 0; t < DIM / 4; ++t) {
        float4 a = fr[t], b = qr[t];
        s = fmaf(a.x, b.x, s); s = fmaf(a.y, b.y, s);
        s = fmaf(a.z, b.z, s); s = fmaf(a.w, b.w, s);
      }
      int bin = (int)((s + 1.0f) * (NBSEL * 0.5f));
      bin = bin < 0 ? 0 : (bin > NBSEL - 1 ? NBSEL - 1 : bin);
      atomicAdd(&hist[bin], 1);
    }
    __syncthreads();

    { int s = 0;
#pragma unroll
      for (int i = 0; i < NBSEL / NT; ++i) s += hist[tid * (NBSEL / NT) + i];
      seg[tid] = s; }
    __syncthreads();
    for (int off = 1; off < NT; off <<= 1) {
      int t = (tid + off < NT) ? seg[tid + off] : 0;
      __syncthreads();
      seg[tid] += t;
      __syncthreads();
    }
    { int run = (tid < NT - 1) ? seg[tid + 1] : 0;
      for (int i = tid * (NBSEL / NT) + NBSEL / NT - 1;
           i >= tid * (NBSEL / NT); --i) {
        run += hist[i];
        if (run >= KNN) { atomicMax(&s_b, i); break; }
      } }
    __syncthreads();
    const int bstar = s_b;

    for (int q = tid; q < NQ; q += NT) {
      const float4* qr = (const float4*)(qf + (size_t)q * DIM);
      const float4* fr = (const float4*)frow;
      float s = 0.0f;
#pragma unroll
      for (int t = 0; t < DIM / 4; ++t) {
        float4 a = fr[t], b = qr[t];
        s = fmaf(a.x, b.x, s); s = fmaf(a.y, b.y, s);
        s = fmaf(a.z, b.z, s); s = fmaf(a.w, b.w, s);
      }
      int bin = (int)((s + 1.0f) * (NBSEL * 0.5f));
      bin = bin < 0 ? 0 : (bin > NBSEL - 1 ? NBSEL - 1 : bin);
      if (bin >= bstar) {
        int p = atomicAdd(&s_cnt, 1);
        if (p < CCAP) { candV[p] = s; candI[p] = q; }
      }
    }
    __syncthreads();
    int m = s_cnt < CCAP ? s_cnt : CCAP;

    int P = 256; while (P < m) P <<= 1;
    for (int i = tid; i < P; i += NT)
      if (i >= m) { candV[i] = -INFINITY; candI[i] = 0x7fffffff; }
    __syncthreads();
    for (int k = 2; k <= P; k <<= 1) {
      for (int j = k >> 1; j > 0; j >>= 1) {
        for (int i = tid; i < P; i += NT) {
          int ixj = i ^ j;
          if (ixj > i) {
            float va = candV[i], vb = candV[ixj];
            int ia = candI[i], ib = candI[ixj];
            bool aFirst = (va > vb) || (va == vb && ia < ib);
            bool up = ((i & k) == 0);
            if (up ? !aFirst : aFirst) {
              candV[i] = vb; candV[ixj] = va;
              candI[i] = ib; candI[ixj] = ia;
            }
          }
        }
        __syncthreads();
      }
    }

    for (int c = tid; c < NCLS; c += NT) votes[c] = 0.0f;
    __syncthreads();
    for (int i = tid; i < KNN; i += NT)
      atomicAdd(&votes[qlab[candI[i]]], expf(candV[i] * (1.0f / 0.07f)));
    __syncthreads();
  }

  // ---- common argmax (lowest class index on tie) + accuracy ----
  u64 key = 0ull;
  for (int c = tid; c < NCLS; c += NT) {
    u64 k2 = ((u64)__float_as_uint(votes[c]) << 32) |
             (u64)(0xFFFFFFFFu - (unsigned)c);
    if (k2 > key) key = k2;
  }
  for (int off = 32; off > 0; off >>= 1) {
    u64 o = __shfl_down(key, off, 64);
    if (o > key) key = o;
  }
  if ((tid & 63) == 0) atomicMax(&s_best, key);
  __syncthreads();
  if (tid == 0) {
    int cls = (int)(0xFFFFFFFFu - (unsigned)(s_best & 0xFFFFFFFFull));
    if (cls == labels[row]) atomicAdd(out, inv_n);
  }
}

// ---------------------------------------------------------------------------
extern "C" void kernel_launch(void* const* d_in, const int* in_sizes, int n_in,
                              void* d_out, int out_size, void* d_ws, size_t ws_size,
                              hipStream_t stream)
{
  const float* features = (const float*)d_in[0];
  const int*   labels   = (const int*)d_in[1];
  const float* qfeat    = (const float*)d_in[2];
  const int*   qlab     = (const int*)d_in[3];
  const int*   qptr     = (const int*)d_in[4];
  float* out = (float*)d_out;

  int nbatch = in_sizes[0] / DIM;             // 512
  float inv_n = 1.0f / (float)nbatch;

  // ws layout: [B 32MB][cand uint2][cnt2 1MB][flag 2KB][A 256KB]
  size_t bBytes = (size_t)NQ * DIM * 2;                 // 32 MiB
  size_t fixed  = bBytes + (size_t)NBATCH * NTN * 4 + NBATCH * 4 +
                  (size_t)NBATCH * DIM * 2;
  int SLOT = 16;
  while ((size_t)NBATCH * NTN * SLOT * 8 + fixed > ws_size && SLOT > 2) SLOT >>= 1;

  u16*   Bb   = (u16*)d_ws;
  uint2* cand = (uint2*)((char*)d_ws + bBytes);
  int*   cnt2 = (int*)((char*)cand + (size_t)NBATCH * NTN * SLOT * 8);
  int*   flagp = cnt2 + (size_t)NBATCH * NTN;
  u16*   Ab   = (u16*)(flagp + NBATCH);

  prep_copy_kernel<<<NQ * DIM / 4 / 256, 256, 0, stream>>>(
      features, labels, qfeat, qlab, qptr, Bb, Ab, flagp, out);

  gemm_mfma<<<(NBATCH / GM) * (NQ / GM), 256, 0, stream>>>(
      Ab, Bb, cand, cnt2, flagp, SLOT);

  select_kernel<<<nbatch, NT, 0, stream>>>(cand, cnt2, flagp, labels, qlab,
                                           qfeat, features, out, inv_n, SLOT);
}